// Round 1
// baseline (711.592 us; speedup 1.0000x reference)
//
#include <hip/hip_runtime.h>
#include <math.h>

// Qwen3Next GatedDeltaNet decode, MI355X.
// Sizes fixed by the reference: B=256, QKV=8192, NK=16, NV=32, HK=HV=128, GROUP=2.
#define QKV   8192
#define NKH   16
#define NVH   32
#define HK    128
#define HV    128
#define QSCALE 0.08838834764831845f   // 128^-0.5

// ---------------------------------------------------------------------------
// Kernel 1: conv1d-update + SiLU + per-head L2 norm (q,k) / passthrough (v).
// One block of 128 threads per (batch, 128-channel head chunk). 64 chunks:
// chunks 0..15 = q heads, 16..31 = k heads, 32..63 = v heads.
// ---------------------------------------------------------------------------
__global__ __launch_bounds__(128) void prep_kernel(
    const float* __restrict__ mixed_qkv,
    const float* __restrict__ conv_state,
    const float* __restrict__ conv_w,
    float* __restrict__ xq, float* __restrict__ xk, float* __restrict__ xv)
{
    __shared__ float red[2];
    const int b   = blockIdx.x >> 6;
    const int hh  = blockIdx.x & 63;
    const int tid = threadIdx.x;
    const int c   = hh * 128 + tid;

    // conv_weights is [QKV, 4] row-major -> one float4 per channel.
    const float4 w = ((const float4*)conv_w)[c];
    const float* cs = conv_state + (size_t)b * (3 * QKV) + c;
    const float  m  = mixed_qkv[(size_t)b * QKV + c];
    const float conv = cs[0] * w.x + cs[QKV] * w.y + cs[2 * QKV] * w.z + m * w.w;
    const float xval = conv / (1.0f + expf(-conv));   // SiLU

    if (hh < 32) {
        // q or k head: L2 normalize over the 128 channels of this head.
        float ss = xval * xval;
        #pragma unroll
        for (int msk = 1; msk < 64; msk <<= 1) ss += __shfl_xor(ss, msk, 64);
        if ((tid & 63) == 0) red[tid >> 6] = ss;
        __syncthreads();
        const float rn = 1.0f / sqrtf(red[0] + red[1] + 1e-6f);
        if (hh < 16) {
            xq[((size_t)b * NKH + hh) * HK + tid] = xval * rn * QSCALE;
        } else {
            xk[((size_t)b * NKH + (hh - 16)) * HK + tid] = xval * rn;
        }
    } else {
        xv[((size_t)b * NVH + (hh - 32)) * HV + tid] = xval;
    }
}

// ---------------------------------------------------------------------------
// Kernel 2: fused gated delta rule, one block of 256 threads per (b, h).
// Never materializes S_new:
//   o[v] = eg*Sq[v] + beta*(v[v] - eg*Sk[v]) * (kn . qn)
// with Sk/Sq the per-row dots of the old state against kn/qn.
// Streaming read of the 64 KiB state tile is fully coalesced float4.
// ---------------------------------------------------------------------------
__global__ __launch_bounds__(256) void gdn_kernel(
    const float* __restrict__ ssm,
    const float* __restrict__ xq, const float* __restrict__ xk,
    const float* __restrict__ xv,
    const float* __restrict__ a_in, const float* __restrict__ b_in,
    const float* __restrict__ alog, const float* __restrict__ dt_bias,
    float* __restrict__ out)
{
    __shared__ __align__(16) float qn_s[HK];
    __shared__ __align__(16) float kn_s[HK];
    __shared__ float Sk_s[HV];
    __shared__ float Sq_s[HV];
    __shared__ float red[2];
    __shared__ float sc[2];   // sc[0]=exp(g), sc[1]=beta

    const int bh  = blockIdx.x;
    const int b   = bh >> 5;
    const int h   = bh & 31;
    const int kh  = h >> 1;          // GQA: v-head h uses k-head h/2
    const int tid = threadIdx.x;

    if (tid < 128) {
        const float q = xq[((size_t)b * NKH + kh) * HK + tid];
        const float k = xk[((size_t)b * NKH + kh) * HK + tid];
        qn_s[tid] = q;
        kn_s[tid] = k;
        float p = q * k;
        #pragma unroll
        for (int msk = 1; msk < 64; msk <<= 1) p += __shfl_xor(p, msk, 64);
        if ((tid & 63) == 0) red[tid >> 6] = p;
    } else if (tid == 128) {
        const float av = a_in[b * NVH + h] + dt_bias[h];
        const float sp = (av > 20.0f) ? av : log1pf(expf(av));
        const float g  = -expf(alog[h]) * sp;
        sc[0] = expf(g);
        sc[1] = 1.0f / (1.0f + expf(-b_in[b * NVH + h]));
    }
    __syncthreads();

    const float kq   = red[0] + red[1];
    const float eg   = sc[0];
    const float beta = sc[1];

    // Thread's 4-element k/q fragment is constant across the whole loop.
    const float4 k4 = ((const float4*)kn_s)[tid & 31];
    const float4 q4 = ((const float4*)qn_s)[tid & 31];

    const float4* Sp = (const float4*)(ssm + (size_t)bh * (HV * HK));
    #pragma unroll
    for (int j = 0; j < 16; ++j) {
        const int f = tid + j * 256;           // float4 index; row = f>>5
        const float4 s = Sp[f];
        float pk = s.x * k4.x + s.y * k4.y + s.z * k4.z + s.w * k4.w;
        float pq = s.x * q4.x + s.y * q4.y + s.z * q4.z + s.w * q4.w;
        // reduce across the 32 lanes covering one row
        #pragma unroll
        for (int msk = 1; msk < 32; msk <<= 1) {
            pk += __shfl_xor(pk, msk, 64);
            pq += __shfl_xor(pq, msk, 64);
        }
        if ((tid & 31) == 0) {
            const int v = f >> 5;
            Sk_s[v] = pk;
            Sq_s[v] = pq;
        }
    }
    __syncthreads();

    if (tid < 128) {
        const float vin   = xv[((size_t)b * NVH + h) * HV + tid];
        const float vold  = eg * Sk_s[tid];
        const float delta = beta * (vin - vold);
        out[(size_t)bh * HV + tid] = eg * Sq_s[tid] + delta * kq;
    }
}

extern "C" void kernel_launch(void* const* d_in, const int* in_sizes, int n_in,
                              void* d_out, int out_size, void* d_ws, size_t ws_size,
                              hipStream_t stream) {
    const float* mixed_qkv  = (const float*)d_in[0];
    const float* b_in       = (const float*)d_in[1];
    const float* a_in       = (const float*)d_in[2];
    const float* conv_state = (const float*)d_in[3];
    const float* conv_w     = (const float*)d_in[4];
    const float* ssm        = (const float*)d_in[5];
    const float* alog       = (const float*)d_in[6];
    const float* dt_bias    = (const float*)d_in[7];
    float* out = (float*)d_out;

    const int B = in_sizes[0] / QKV;   // 256

    float* xq = (float*)d_ws;                       // B*NKH*HK floats
    float* xk = xq + (size_t)B * NKH * HK;          // B*NKH*HK floats
    float* xv = xk + (size_t)B * NKH * HK;          // B*NVH*HV floats

    prep_kernel<<<B * 64, 128, 0, stream>>>(mixed_qkv, conv_state, conv_w, xq, xk, xv);
    gdn_kernel<<<B * NVH, 256, 0, stream>>>(ssm, xq, xk, xv, a_in, b_in,
                                            alog, dt_bias, out);
}